// Round 2
// baseline (2080.520 us; speedup 1.0000x reference)
//
#include <hip/hip_runtime.h>
#include <cstdint>
#include <cstddef>

#define B_ 512
#define T_ 2048
#define D_ 64
#define H_ 48
#define C_ 3
#define TT 32
#define NT 256
#define NW 192   // worker threads (3 waves)

__global__ __launch_bounds__(NT, 2) void snn_pipe(
    const float* __restrict__ x,
    const float* __restrict__ Wenc, const float* __restrict__ benc,
    const float* __restrict__ Wmem, const float* __restrict__ bmem,
    const float* __restrict__ Wdec, const float* __restrict__ bdec,
    const float* __restrict__ Wcls, const float* __restrict__ bcls,
    float* __restrict__ out)
{
    // strides chosen for conflict-free broadcast reads (see round-2 analysis)
    __shared__ float sWenc[H_][68];
    __shared__ float sWdec[D_][52];
    __shared__ float sx[2][TT][68];
    __shared__ float su[2][TT][52];
    __shared__ float sz[2][TT][52];
    __shared__ float sbe[H_], sbd[D_], szsum[H_];

    const int tid  = threadIdx.x;
    const int b    = blockIdx.x;
    const int lane = tid & 63;
    const int wv   = tid >> 6;
    const int recw = b & 3;               // spread rec waves across SIMDs between blocks
    const bool isrec = (wv == recw);
    const int wrk  = wv - (wv > recw ? 1 : 0);
    const int u    = wrk * 64 + lane;     // worker index 0..191 (unused on rec wave)

    // ---- stage weights / biases ----
    for (int idx = tid; idx < H_ * D_; idx += NT) sWenc[idx >> 6][idx & 63] = Wenc[idx];
    for (int idx = tid; idx < D_ * H_; idx += NT) { int d = idx / H_; sWdec[d][idx - d * H_] = Wdec[idx]; }
    if (tid < H_) sbe[tid] = benc[tid] + bmem[tid];
    if (tid < D_) sbd[tid] = bdec[tid];

    // rec-wave per-lane W_mem row (0.1 pre-folded); lanes>=48 mirror lane 0 (harmless)
    float wm[H_];
    {
        const int hh = lane < H_ ? lane : 0;
        #pragma unroll
        for (int j = 0; j < H_; ++j) wm[j] = 0.1f * Wmem[hh * H_ + j];
    }
    float memreg = 0.f, zs = 0.f;

    const float* xb     = x   + (size_t)b * T_ * D_;
    float*       reconb = out + (size_t)b * T_ * D_;
    float*       logitg = out + (size_t)B_ * T_ * D_ + (size_t)b * C_;
    float*       zb     = out + (size_t)B_ * T_ * D_ + (size_t)B_ * C_ + (size_t)b * T_ * H_;

    // ---- worker lambdas ----
    auto xload_tile = [&](int j) {             // stage x(j) into sx[j&1]
        const int bb = j & 1;
        const float* src = xb + (size_t)j * TT * D_;
        for (int k = u; k < TT * 16; k += NW) {
            int s = k >> 4, d4 = k & 15;
            *reinterpret_cast<float4*>(&sx[bb][s][d4 * 4]) =
                *reinterpret_cast<const float4*>(src + (size_t)s * D_ + d4 * 4);
        }
    };

    auto enc_tile = [&](int j) {               // su[j&1] = x(j)@Wenc^T + (benc+bmem)
        const int bb = j & 1;
        const int s = u / 6, hg = u - s * 6;   // u<192 -> s 0..31, hg 0..5
        float4 xc[16];
        #pragma unroll
        for (int m = 0; m < 16; ++m) xc[m] = *reinterpret_cast<const float4*>(&sx[bb][s][m * 4]);
        #pragma unroll
        for (int k = 0; k < 8; ++k) {
            const int h = hg + 6 * k;
            const float4* wr = reinterpret_cast<const float4*>(sWenc[h]);
            float a0 = 0.f, a1 = 0.f, a2 = 0.f, a3 = 0.f;
            #pragma unroll
            for (int m = 0; m < 16; ++m) {
                float4 xv = xc[m], wv = wr[m];
                a0 = fmaf(xv.x, wv.x, a0); a1 = fmaf(xv.y, wv.y, a1);
                a2 = fmaf(xv.z, wv.z, a2); a3 = fmaf(xv.w, wv.w, a3);
            }
            su[bb][s][h] = sbe[h] + ((a0 + a1) + (a2 + a3));
        }
    };

    auto dec_rows = [&](int j, int s, int dg) {  // 8 outputs of recon row (j*TT+s)
        const int bz = j & 1;
        float4 zc[12];
        #pragma unroll
        for (int m = 0; m < 12; ++m) zc[m] = *reinterpret_cast<const float4*>(&sz[bz][s][m * 4]);
        #pragma unroll
        for (int k = 0; k < 8; ++k) {
            const int d = dg + 8 * k;
            const float4* wr = reinterpret_cast<const float4*>(sWdec[d]);
            float a0 = 0.f, a1 = 0.f, a2 = 0.f, a3 = 0.f;
            #pragma unroll
            for (int m = 0; m < 12; ++m) {
                float4 zv = zc[m], wv = wr[m];
                a0 = fmaf(zv.x, wv.x, a0); a1 = fmaf(zv.y, wv.y, a1);
                a2 = fmaf(zv.z, wv.z, a2); a3 = fmaf(zv.w, wv.w, a3);
            }
            reconb[(size_t)(j * TT + s) * D_ + d] = sbd[d] + ((a0 + a1) + (a2 + a3));
        }
    };

    auto dec_tile = [&](int j) {
        dec_rows(j, u >> 3, u & 7);                       // s 0..23
        if (u < 64) dec_rows(j, 24 + (u >> 3), u & 7);    // s 24..31
    };

    // ---- prologue: x(0), x(1); enc(0) ----
    for (int k = tid; k < 2 * TT * 16; k += NT) {
        int bb = k >> 9, s = (k >> 4) & 31, d4 = k & 15;
        *reinterpret_cast<float4*>(&sx[bb][s][d4 * 4]) =
            *reinterpret_cast<const float4*>(xb + (size_t)(bb * TT + s) * D_ + d4 * 4);
    }
    __syncthreads();
    if (!isrec) enc_tile(0);
    __syncthreads();

    // ---- main pipeline: one barrier per tile ----
    for (int i = 0; i < T_ / TT; ++i) {
        if (isrec) {
            const int bi = i & 1;
            const int lh = lane < H_ ? lane : 0;
            for (int s = 0; s < TT; ++s) {
                const float suval = su[bi][s][lh];
                float a0 = 0.f, a1 = 0.f, a2 = 0.f, a3 = 0.f;
                #pragma unroll
                for (int j = 0; j < H_; j += 4) {
                    float m0 = __int_as_float(__builtin_amdgcn_readlane(__float_as_int(memreg), j));
                    float m1 = __int_as_float(__builtin_amdgcn_readlane(__float_as_int(memreg), j + 1));
                    float m2 = __int_as_float(__builtin_amdgcn_readlane(__float_as_int(memreg), j + 2));
                    float m3 = __int_as_float(__builtin_amdgcn_readlane(__float_as_int(memreg), j + 3));
                    a0 = fmaf(m0, wm[j],     a0);
                    a1 = fmaf(m1, wm[j + 1], a1);
                    a2 = fmaf(m2, wm[j + 2], a2);
                    a3 = fmaf(m3, wm[j + 3], a3);
                }
                memreg = fmaf(0.9f, memreg, fmaf(0.1f, suval, (a0 + a1) + (a2 + a3)));
                const float zz = 1.0f / (1.0f + __expf(-memreg));
                if (lane < H_) {
                    zb[(size_t)(i * TT + s) * H_ + lane] = zz;
                    sz[bi][s][lane] = zz;
                    zs += zz;
                }
            }
        } else {
            if (i >= 1)  dec_tile(i - 1);
            if (i <= 62) enc_tile(i + 1);
            if (i <= 61) xload_tile(i + 2);
        }
        __syncthreads();
    }

    // ---- epilogue: dec(63), classifier ----
    if (!isrec) dec_tile(T_ / TT - 1);
    if (isrec && lane < H_) szsum[lane] = zs;
    __syncthreads();
    if (tid < C_) {
        float acc = 0.f;
        #pragma unroll
        for (int h = 0; h < H_; ++h) acc = fmaf(szsum[h], Wcls[tid * H_ + h], acc);
        logitg[tid] = acc * (1.0f / (float)T_) + bcls[tid];
    }
}

extern "C" void kernel_launch(void* const* d_in, const int* in_sizes, int n_in,
                              void* d_out, int out_size, void* d_ws, size_t ws_size,
                              hipStream_t stream) {
    const float* x    = (const float*)d_in[0];
    const float* Wenc = (const float*)d_in[1];
    const float* benc = (const float*)d_in[2];
    const float* Wmem = (const float*)d_in[3];
    const float* bmem = (const float*)d_in[4];
    const float* Wdec = (const float*)d_in[5];
    const float* bdec = (const float*)d_in[6];
    const float* Wcls = (const float*)d_in[7];
    const float* bcls = (const float*)d_in[8];

    snn_pipe<<<dim3(B_), dim3(NT), 0, stream>>>(
        x, Wenc, benc, Wmem, bmem, Wdec, bdec, Wcls, bcls, (float*)d_out);
}

// Round 4
// 1051.983 us; speedup vs baseline: 1.9777x; 1.9777x over previous
//
#include <hip/hip_runtime.h>
#include <cstdint>
#include <cstddef>

#define B_ 512
#define T_ 2048
#define D_ 64
#define H_ 48
#define C_ 3

#define RECON_FLOATS ((size_t)B_ * T_ * D_)            // 67,108,864 floats (output 0)
#define LOGIT_FLOATS ((size_t)B_ * C_)                 // 1536 floats      (output 1)
#define Z_OFF        (RECON_FLOATS + LOGIT_FLOATS)     // z region         (output 2)
// u stash (f32, 50,331,648 floats) lives at out[0..) inside the recon region; dec overwrites it last.
#define ZSUM_STASH   (RECON_FLOATS - 32768)            // zsum stash (24K floats), after u end, before dec

// ---------------- encoder: u[b,t,h] = x row . Wenc^T + (benc+bmem), f32 stash ----------------
__global__ __launch_bounds__(256) void k_enc(
    const float* __restrict__ x, const float* __restrict__ Wenc,
    const float* __restrict__ benc, const float* __restrict__ bmem,
    float* __restrict__ out)
{
    __shared__ float sW[16][48][4];   // sW[d4][h][c] = Wenc[h][4*d4+c] -> wave-uniform broadcast reads
    __shared__ float sb[48];
    const int tid = threadIdx.x;
    for (int idx = tid; idx < 48 * 64; idx += 256) {
        int h = idx >> 6, d = idx & 63;
        sW[d >> 2][h][d & 3] = Wenc[idx];
    }
    if (tid < 48) sb[tid] = benc[tid] + bmem[tid];
    __syncthreads();

    const size_t r = (size_t)blockIdx.x * 256 + tid;   // row (b,t)
    const float* xr = x + r * 64;

    float acc[48];
    #pragma unroll
    for (int h = 0; h < 48; ++h) acc[h] = sb[h];

    #pragma unroll 4
    for (int d4 = 0; d4 < 16; ++d4) {
        const float4 xv = *reinterpret_cast<const float4*>(xr + d4 * 4);
        #pragma unroll
        for (int h = 0; h < 48; ++h) {
            const float4 wv = *reinterpret_cast<const float4*>(sW[d4][h]);
            acc[h] = fmaf(xv.x, wv.x, fmaf(xv.y, wv.y, fmaf(xv.z, wv.z, fmaf(xv.w, wv.w, acc[h]))));
        }
    }

    float4* dst = reinterpret_cast<float4*>(out + r * 48);
    #pragma unroll
    for (int j = 0; j < 12; ++j)
        dst[j] = make_float4(acc[4 * j], acc[4 * j + 1], acc[4 * j + 2], acc[4 * j + 3]);
}

// ---------------- recurrence: 1 wave per batch element, readlane-broadcast matvec ----------------
__global__ __launch_bounds__(64) void k_rec(
    const float* __restrict__ Wmem, float* __restrict__ out)
{
    const int lane = threadIdx.x;
    const int b    = blockIdx.x;
    const int h    = lane < H_ ? lane : 0;

    // ms = 10*mem; 0.1 folded into wm:  ms' = 0.9*ms + (u' + wm.ms),  z = sigmoid(0.1*ms)
    float wm[48];
    #pragma unroll
    for (int j = 0; j < 48; ++j) wm[j] = 0.1f * Wmem[h * 48 + j];

    const float* ub = out + (size_t)b * T_ * 48;          // u stash (f32)
    float*       zb = out + Z_OFF + (size_t)b * T_ * 48;

    __shared__ float su[2][32 * 48];   // tile staging; lane owns global-linear [24*lane, 24*lane+24)

    float4 p[6];
    {
        const float4* s4 = reinterpret_cast<const float4*>(ub);
        #pragma unroll
        for (int k = 0; k < 6; ++k) p[k] = s4[lane * 6 + k];
        #pragma unroll
        for (int k = 0; k < 6; ++k)
            *reinterpret_cast<float4*>(&su[0][lane * 24 + 4 * k]) = p[k];
    }
    __syncthreads();

    float ms = 0.f, zs = 0.f;
    const float kExp = -0.14426950408889634f;  // -0.1 * log2(e)

    for (int tile = 0; tile < T_ / 32; ++tile) {
        const int cur = tile & 1;
        const bool more = (tile + 1) < T_ / 32;
        if (more) {   // issue next-tile global loads now; written to LDS after the 32 steps
            const float4* n4 = reinterpret_cast<const float4*>(ub + (size_t)(tile + 1) * 32 * 48);
            #pragma unroll
            for (int k = 0; k < 6; ++k) p[k] = n4[lane * 6 + k];
        }
        #pragma unroll
        for (int s = 0; s < 32; ++s) {
            // 8 accumulators -> 6-deep FMA chains on the critical path
            float a0 = su[cur][s * 48 + h], a1 = 0.f, a2 = 0.f, a3 = 0.f;
            float a4 = 0.f, a5 = 0.f, a6 = 0.f, a7 = 0.f;
            #pragma unroll
            for (int g = 0; g < 6; ++g) {
                const int j = 8 * g;
                const float m0 = __int_as_float(__builtin_amdgcn_readlane(__float_as_int(ms), j + 0));
                const float m1 = __int_as_float(__builtin_amdgcn_readlane(__float_as_int(ms), j + 1));
                const float m2 = __int_as_float(__builtin_amdgcn_readlane(__float_as_int(ms), j + 2));
                const float m3 = __int_as_float(__builtin_amdgcn_readlane(__float_as_int(ms), j + 3));
                const float m4 = __int_as_float(__builtin_amdgcn_readlane(__float_as_int(ms), j + 4));
                const float m5 = __int_as_float(__builtin_amdgcn_readlane(__float_as_int(ms), j + 5));
                const float m6 = __int_as_float(__builtin_amdgcn_readlane(__float_as_int(ms), j + 6));
                const float m7 = __int_as_float(__builtin_amdgcn_readlane(__float_as_int(ms), j + 7));
                a0 = fmaf(m0, wm[j + 0], a0);
                a1 = fmaf(m1, wm[j + 1], a1);
                a2 = fmaf(m2, wm[j + 2], a2);
                a3 = fmaf(m3, wm[j + 3], a3);
                a4 = fmaf(m4, wm[j + 4], a4);
                a5 = fmaf(m5, wm[j + 5], a5);
                a6 = fmaf(m6, wm[j + 6], a6);
                a7 = fmaf(m7, wm[j + 7], a7);
            }
            const float dot = ((a0 + a1) + (a2 + a3)) + ((a4 + a5) + (a6 + a7));
            ms = fmaf(0.9f, ms, dot);
            // off the critical path:
            const float z = 1.0f / (1.0f + __builtin_amdgcn_exp2f(ms * kExp));
            if (lane < H_) {
                zb[(size_t)(tile * 32 + s) * 48 + lane] = z;
                zs += z;
            }
        }
        if (more) {
            #pragma unroll
            for (int k = 0; k < 6; ++k)
                *reinterpret_cast<float4*>(&su[cur ^ 1][lane * 24 + 4 * k]) = p[k];
            __syncthreads();   // single-wave: cheap; orders DS writes vs next tile's reads
        }
    }

    if (lane < H_) out[ZSUM_STASH + (size_t)b * 48 + lane] = zs;
}

// ---------------- classifier (before dec overwrites the zsum stash) ----------------
__global__ __launch_bounds__(256) void k_cls(
    const float* __restrict__ Wcls, const float* __restrict__ bcls,
    float* __restrict__ out)
{
    const int g = blockIdx.x * 256 + threadIdx.x;
    if (g >= B_ * C_) return;
    const int b = g / C_, c = g - b * C_;
    const float* zsum = out + ZSUM_STASH + (size_t)b * 48;
    float acc = 0.f;
    #pragma unroll
    for (int hh = 0; hh < 48; ++hh) acc = fmaf(zsum[hh], Wcls[c * 48 + hh], acc);
    out[RECON_FLOATS + g] = acc * (1.0f / (float)T_) + bcls[c];
}

// ---------------- decoder: recon row = z row . Wdec^T + bdec ----------------
__global__ __launch_bounds__(256) void k_dec(
    const float* __restrict__ Wdec, const float* __restrict__ bdec,
    float* __restrict__ out)
{
    __shared__ float sW[12][64][4];   // sW[h4][d][c] = Wdec[d][4*h4+c] -> broadcast reads
    __shared__ float sb[64];
    const int tid = threadIdx.x;
    for (int idx = tid; idx < 64 * 48; idx += 256) {
        int d = idx / 48, hh = idx - d * 48;
        sW[hh >> 2][d][hh & 3] = Wdec[idx];
    }
    if (tid < 64) sb[tid] = bdec[tid];
    __syncthreads();

    const size_t r = (size_t)blockIdx.x * 256 + tid;
    const float* zr = out + Z_OFF + r * 48;
    float zrow[48];
    #pragma unroll
    for (int i = 0; i < 12; ++i)
        *reinterpret_cast<float4*>(&zrow[4 * i]) = *reinterpret_cast<const float4*>(zr + 4 * i);

    float* rr = out + r * 64;
    #pragma unroll 4
    for (int dq = 0; dq < 16; ++dq) {
        float4 o;
        #pragma unroll
        for (int c = 0; c < 4; ++c) {
            const int d = dq * 4 + c;
            float a0 = sb[d], a1 = 0.f, a2 = 0.f, a3 = 0.f;
            #pragma unroll
            for (int h4 = 0; h4 < 12; ++h4) {
                const float4 wv = *reinterpret_cast<const float4*>(sW[h4][d]);
                a0 = fmaf(zrow[4 * h4 + 0], wv.x, a0);
                a1 = fmaf(zrow[4 * h4 + 1], wv.y, a1);
                a2 = fmaf(zrow[4 * h4 + 2], wv.z, a2);
                a3 = fmaf(zrow[4 * h4 + 3], wv.w, a3);
            }
            (&o.x)[c] = (a0 + a1) + (a2 + a3);
        }
        *reinterpret_cast<float4*>(rr + dq * 4) = o;
    }
}

extern "C" void kernel_launch(void* const* d_in, const int* in_sizes, int n_in,
                              void* d_out, int out_size, void* d_ws, size_t ws_size,
                              hipStream_t stream) {
    const float* x    = (const float*)d_in[0];
    const float* Wenc = (const float*)d_in[1];
    const float* benc = (const float*)d_in[2];
    const float* Wmem = (const float*)d_in[3];
    const float* bmem = (const float*)d_in[4];
    const float* Wdec = (const float*)d_in[5];
    const float* bdec = (const float*)d_in[6];
    const float* Wcls = (const float*)d_in[7];
    const float* bcls = (const float*)d_in[8];
    float* out = (float*)d_out;

    const int rows = B_ * T_;                       // 1,048,576
    k_enc<<<dim3(rows / 256), dim3(256), 0, stream>>>(x, Wenc, benc, bmem, out);
    k_rec<<<dim3(B_), dim3(64), 0, stream>>>(Wmem, out);
    k_cls<<<dim3((B_ * C_ + 255) / 256), dim3(256), 0, stream>>>(Wcls, bcls, out);
    k_dec<<<dim3(rows / 256), dim3(256), 0, stream>>>(Wdec, bdec, out);
}

// Round 5
// 1050.930 us; speedup vs baseline: 1.9797x; 1.0010x over previous
//
#include <hip/hip_runtime.h>
#include <cstdint>
#include <cstddef>

#define B_ 512
#define T_ 2048
#define D_ 64
#define H_ 48
#define C_ 3

#define RECON_FLOATS ((size_t)B_ * T_ * D_)            // 67,108,864 floats (output 0)
#define LOGIT_FLOATS ((size_t)B_ * C_)                 // 1536 floats      (output 1)
#define Z_OFF        (RECON_FLOATS + LOGIT_FLOATS)     // z region         (output 2)
// u stash (f32, 50,331,648 floats) lives at out[0..) inside the recon region; dec overwrites it last.
#define ZSUM_STASH   (RECON_FLOATS - 32768)            // zsum stash, disjoint from u stash

// ---------------- encoder: u[b,t,h] = x row . Wenc^T + (benc+bmem); 2 rows/thread ----------------
__global__ __launch_bounds__(256) void k_enc(
    const float* __restrict__ x, const float* __restrict__ Wenc,
    const float* __restrict__ benc, const float* __restrict__ bmem,
    float* __restrict__ out)
{
    __shared__ float sW[16][48][4];   // sW[d4][h][c] = Wenc[h][4*d4+c] -> wave-uniform broadcast reads
    __shared__ float sb[48];
    const int tid = threadIdx.x;
    for (int idx = tid; idx < 48 * 64; idx += 256) {
        int h = idx >> 6, d = idx & 63;
        sW[d >> 2][h][d & 3] = Wenc[idx];
    }
    if (tid < 48) sb[tid] = benc[tid] + bmem[tid];
    __syncthreads();

    const size_t r0 = ((size_t)blockIdx.x * 256 + tid) * 2;   // rows r0, r0+1
    const float* xr0 = x + r0 * 64;
    const float* xr1 = xr0 + 64;

    float accA[48], accB[48];
    #pragma unroll
    for (int h = 0; h < 48; ++h) { accA[h] = sb[h]; accB[h] = sb[h]; }

    #pragma unroll 4
    for (int d4 = 0; d4 < 16; ++d4) {
        const float4 xa = *reinterpret_cast<const float4*>(xr0 + d4 * 4);
        const float4 xb = *reinterpret_cast<const float4*>(xr1 + d4 * 4);
        #pragma unroll
        for (int h = 0; h < 48; ++h) {
            const float4 wv = *reinterpret_cast<const float4*>(sW[d4][h]);   // one ds read, two rows
            accA[h] = fmaf(xa.x, wv.x, fmaf(xa.y, wv.y, fmaf(xa.z, wv.z, fmaf(xa.w, wv.w, accA[h]))));
            accB[h] = fmaf(xb.x, wv.x, fmaf(xb.y, wv.y, fmaf(xb.z, wv.z, fmaf(xb.w, wv.w, accB[h]))));
        }
    }

    float4* dstA = reinterpret_cast<float4*>(out + r0 * 48);
    float4* dstB = reinterpret_cast<float4*>(out + (r0 + 1) * 48);
    #pragma unroll
    for (int j = 0; j < 12; ++j) {
        dstA[j] = make_float4(accA[4 * j], accA[4 * j + 1], accA[4 * j + 2], accA[4 * j + 3]);
        dstB[j] = make_float4(accB[4 * j], accB[4 * j + 1], accB[4 * j + 2], accB[4 * j + 3]);
    }
}

// ---------------- recurrence: 1 wave per batch element; u tile register-resident ----------------
__global__ __launch_bounds__(64) void k_rec(
    const float* __restrict__ Wmem, float* __restrict__ out)
{
    const int lane = threadIdx.x;
    const int b    = blockIdx.x;
    const int h    = lane < H_ ? lane : 0;

    // ms = 10*mem; 0.1 folded into wm:  ms' = 0.9*ms + (u' + wm.ms),  z = sigmoid(0.1*ms)
    float wm[48];
    #pragma unroll
    for (int j = 0; j < 48; ++j) wm[j] = 0.1f * Wmem[h * 48 + j];

    const float* ub = out + (size_t)b * T_ * 48;          // u stash (f32)
    float*       zb = out + Z_OFF + (size_t)b * T_ * 48;

    __shared__ float su[2][32 * 48];   // staging; lane owns global-linear [24*lane, 24*lane+24)

    float4 p[6];
    {
        const float4* s4 = reinterpret_cast<const float4*>(ub);
        #pragma unroll
        for (int k = 0; k < 6; ++k) p[k] = s4[lane * 6 + k];
        #pragma unroll
        for (int k = 0; k < 6; ++k)
            *reinterpret_cast<float4*>(&su[0][lane * 24 + 4 * k]) = p[k];
    }
    __syncthreads();

    float ms = 0.f, zs = 0.f;
    const float kExp = -0.14426950408889634f;  // -0.1 * log2(e)

    for (int tile = 0; tile < T_ / 32; ++tile) {
        const int cur = tile & 1;
        const bool more = (tile + 1) < T_ / 32;

        // issue next-tile global loads first (long latency, fully hidden under compute)
        if (more) {
            const float4* n4 = reinterpret_cast<const float4*>(ub + (size_t)(tile + 1) * 32 * 48);
            #pragma unroll
            for (int k = 0; k < 6; ++k) p[k] = n4[lane * 6 + k];
        }

        // pre-read this tile's 32 u values into registers: one lgkm wait per tile,
        // serial loop below is pure VALU (no LDS on the critical path)
        float uu[32];
        #pragma unroll
        for (int s = 0; s < 32; ++s) uu[s] = su[cur][s * 48 + h];

        #pragma unroll
        for (int s = 0; s < 32; ++s) {
            float a0 = uu[s];
            float a1 = 0.9f * ms;          // folds the leak term into an accumulator chain
            float a2 = 0.f, a3 = 0.f, a4 = 0.f, a5 = 0.f, a6 = 0.f, a7 = 0.f;
            #pragma unroll
            for (int g = 0; g < 6; ++g) {
                const int j = 8 * g;
                const float m0 = __int_as_float(__builtin_amdgcn_readlane(__float_as_int(ms), j + 0));
                const float m1 = __int_as_float(__builtin_amdgcn_readlane(__float_as_int(ms), j + 1));
                const float m2 = __int_as_float(__builtin_amdgcn_readlane(__float_as_int(ms), j + 2));
                const float m3 = __int_as_float(__builtin_amdgcn_readlane(__float_as_int(ms), j + 3));
                const float m4 = __int_as_float(__builtin_amdgcn_readlane(__float_as_int(ms), j + 4));
                const float m5 = __int_as_float(__builtin_amdgcn_readlane(__float_as_int(ms), j + 5));
                const float m6 = __int_as_float(__builtin_amdgcn_readlane(__float_as_int(ms), j + 6));
                const float m7 = __int_as_float(__builtin_amdgcn_readlane(__float_as_int(ms), j + 7));
                a0 = fmaf(m0, wm[j + 0], a0);
                a1 = fmaf(m1, wm[j + 1], a1);
                a2 = fmaf(m2, wm[j + 2], a2);
                a3 = fmaf(m3, wm[j + 3], a3);
                a4 = fmaf(m4, wm[j + 4], a4);
                a5 = fmaf(m5, wm[j + 5], a5);
                a6 = fmaf(m6, wm[j + 6], a6);
                a7 = fmaf(m7, wm[j + 7], a7);
            }
            ms = ((a0 + a1) + (a2 + a3)) + ((a4 + a5) + (a6 + a7));
            // dead-end ops (never feed back): approx rcp is safe
            const float e = __builtin_amdgcn_exp2f(ms * kExp);
            const float z = __builtin_amdgcn_rcpf(1.0f + e);
            if (lane < H_) {
                zb[(size_t)(tile * 32 + s) * 48 + lane] = z;
                zs += z;
            }
        }

        if (more) {
            #pragma unroll
            for (int k = 0; k < 6; ++k)
                *reinterpret_cast<float4*>(&su[cur ^ 1][lane * 24 + 4 * k]) = p[k];
            __syncthreads();   // single wave: cheap; orders DS writes vs next tile's reads
        }
    }

    if (lane < H_) out[ZSUM_STASH + (size_t)b * 48 + lane] = zs;
}

// ---------------- classifier (before dec overwrites the zsum stash) ----------------
__global__ __launch_bounds__(256) void k_cls(
    const float* __restrict__ Wcls, const float* __restrict__ bcls,
    float* __restrict__ out)
{
    const int g = blockIdx.x * 256 + threadIdx.x;
    if (g >= B_ * C_) return;
    const int b = g / C_, c = g - b * C_;
    const float* zsum = out + ZSUM_STASH + (size_t)b * 48;
    float acc = 0.f;
    #pragma unroll
    for (int hh = 0; hh < 48; ++hh) acc = fmaf(zsum[hh], Wcls[c * 48 + hh], acc);
    out[RECON_FLOATS + g] = acc * (1.0f / (float)T_) + bcls[c];
}

// ---------------- decoder: recon row = z row . Wdec^T + bdec; 2 rows/thread ----------------
__global__ __launch_bounds__(256) void k_dec(
    const float* __restrict__ Wdec, const float* __restrict__ bdec,
    float* __restrict__ out)
{
    __shared__ float sW[12][64][4];   // sW[h4][d][c] = Wdec[d][4*h4+c] -> broadcast reads
    __shared__ float sb[64];
    const int tid = threadIdx.x;
    for (int idx = tid; idx < 64 * 48; idx += 256) {
        int d = idx / 48, hh = idx - d * 48;
        sW[hh >> 2][d][hh & 3] = Wdec[idx];
    }
    if (tid < 64) sb[tid] = bdec[tid];
    __syncthreads();

    const size_t r0 = ((size_t)blockIdx.x * 256 + tid) * 2;
    const float* zrA = out + Z_OFF + r0 * 48;
    const float* zrB = zrA + 48;
    float zA[48], zB[48];
    #pragma unroll
    for (int i = 0; i < 12; ++i) {
        *reinterpret_cast<float4*>(&zA[4 * i]) = *reinterpret_cast<const float4*>(zrA + 4 * i);
        *reinterpret_cast<float4*>(&zB[4 * i]) = *reinterpret_cast<const float4*>(zrB + 4 * i);
    }

    float* rrA = out + r0 * 64;
    float* rrB = rrA + 64;
    #pragma unroll 4
    for (int dq = 0; dq < 16; ++dq) {
        float4 oA, oB;
        #pragma unroll
        for (int c = 0; c < 4; ++c) {
            const int d = dq * 4 + c;
            float a0 = sb[d], a1 = 0.f, a2 = 0.f, a3 = 0.f;
            float b0 = sb[d], b1 = 0.f, b2 = 0.f, b3 = 0.f;
            #pragma unroll
            for (int h4 = 0; h4 < 12; ++h4) {
                const float4 wv = *reinterpret_cast<const float4*>(sW[h4][d]);  // one ds read, two rows
                a0 = fmaf(zA[4 * h4 + 0], wv.x, a0);
                a1 = fmaf(zA[4 * h4 + 1], wv.y, a1);
                a2 = fmaf(zA[4 * h4 + 2], wv.z, a2);
                a3 = fmaf(zA[4 * h4 + 3], wv.w, a3);
                b0 = fmaf(zB[4 * h4 + 0], wv.x, b0);
                b1 = fmaf(zB[4 * h4 + 1], wv.y, b1);
                b2 = fmaf(zB[4 * h4 + 2], wv.z, b2);
                b3 = fmaf(zB[4 * h4 + 3], wv.w, b3);
            }
            (&oA.x)[c] = (a0 + a1) + (a2 + a3);
            (&oB.x)[c] = (b0 + b1) + (b2 + b3);
        }
        *reinterpret_cast<float4*>(rrA + dq * 4) = oA;
        *reinterpret_cast<float4*>(rrB + dq * 4) = oB;
    }
}

extern "C" void kernel_launch(void* const* d_in, const int* in_sizes, int n_in,
                              void* d_out, int out_size, void* d_ws, size_t ws_size,
                              hipStream_t stream) {
    const float* x    = (const float*)d_in[0];
    const float* Wenc = (const float*)d_in[1];
    const float* benc = (const float*)d_in[2];
    const float* Wmem = (const float*)d_in[3];
    const float* bmem = (const float*)d_in[4];
    const float* Wdec = (const float*)d_in[5];
    const float* bdec = (const float*)d_in[6];
    const float* Wcls = (const float*)d_in[7];
    const float* bcls = (const float*)d_in[8];
    float* out = (float*)d_out;

    const int blocks2 = (B_ * T_) / 512;            // 2048 blocks, 2 rows/thread
    k_enc<<<dim3(blocks2), dim3(256), 0, stream>>>(x, Wenc, benc, bmem, out);
    k_rec<<<dim3(B_), dim3(64), 0, stream>>>(Wmem, out);
    k_cls<<<dim3((B_ * C_ + 255) / 256), dim3(256), 0, stream>>>(Wcls, bcls, out);
    k_dec<<<dim3(blocks2), dim3(256), 0, stream>>>(Wdec, bdec, out);
}